// Round 1
// baseline (690.448 us; speedup 1.0000x reference)
//
#include <hip/hip_runtime.h>
#include <hip/hip_bf16.h>

typedef __attribute__((ext_vector_type(8))) __bf16 bf16x8;
typedef __attribute__((ext_vector_type(4))) float f32x4;

#define MFMA16(a,b,c) __builtin_amdgcn_mfma_f32_16x16x32_bf16(a,b,c,0,0,0)

__device__ __forceinline__ void gload_lds16(const void* g, void* l) {
  __builtin_amdgcn_global_load_lds(
      (const __attribute__((address_space(1))) void*)g,
      (__attribute__((address_space(3))) void*)l, 16, 0, 0);
}

__device__ __forceinline__ f32x4 max4(f32x4 a, f32x4 b) {
  f32x4 c;
  c[0] = fmaxf(a[0], b[0]); c[1] = fmaxf(a[1], b[1]);
  c[2] = fmaxf(a[2], b[2]); c[3] = fmaxf(a[3], b[3]);
  return c;
}

// ---------------------------------------------------------------------------
// prep: cast weights to bf16, build rel-pos bias table [16][49][49]
// ---------------------------------------------------------------------------
__global__ void prep_k(const float* __restrict__ qkv_w, const float* __restrict__ out_w,
                       const float* __restrict__ rpt,
                       __bf16* __restrict__ qwb, __bf16* __restrict__ owb,
                       float* __restrict__ bias)
{
  int i = blockIdx.x * 256 + threadIdx.x;
  if (i < 786432) { qwb[i] = (__bf16)qkv_w[i]; return; }
  i -= 786432;
  if (i < 262144) { owb[i] = (__bf16)out_w[i]; return; }
  i -= 262144;
  if (i < 38416) {
    int hh = i / 2401, ij = i % 2401;
    int row = ij / 49, col = ij % 49;
    int dh = row / 7 - col / 7 + 6;
    int dw = row % 7 - col % 7 + 6;
    bias[i] = rpt[(dh * 13 + dw) * 16 + hh];
  }
}

// ---------------------------------------------------------------------------
// cast hidden_states f32 -> bf16 (8 elems/thread)
// ---------------------------------------------------------------------------
__global__ void cast_k(const float* __restrict__ in, __bf16* __restrict__ outb, int n8)
{
  int i = blockIdx.x * blockDim.x + threadIdx.x;
  int stride = gridDim.x * blockDim.x;
  for (; i < n8; i += stride) {
    const float4* p = (const float4*)in + (size_t)i * 2;
    float4 x = p[0], y = p[1];
    bf16x8 o;
    o[0] = (__bf16)x.x; o[1] = (__bf16)x.y; o[2] = (__bf16)x.z; o[3] = (__bf16)x.w;
    o[4] = (__bf16)y.x; o[5] = (__bf16)y.y; o[6] = (__bf16)y.z; o[7] = (__bf16)y.w;
    ((bf16x8*)outb)[i] = o;
  }
}

// ---------------------------------------------------------------------------
// GEMM  C[m,n] = sum_k A[m,k] * Bt[n,k]   (A: [M][K] bf16, Bt: [N][K] bf16)
// 128x128 tile, BK=32, 4 waves of 64x64, global_load_lds staging.
// EPI 0: qkv scatter epilogue (+bias, q scaled, write bf16 [B,H,49,32])
// EPI 1: plain epilogue (+bias, fp32 out [M][N])
// ---------------------------------------------------------------------------
template<int EPI>
__global__ __launch_bounds__(256, 3)
void gemm_bt(const __bf16* __restrict__ A, const __bf16* __restrict__ Bt,
             const float* __restrict__ bvec, float* __restrict__ outp,
             __bf16* __restrict__ qb, __bf16* __restrict__ kb, __bf16* __restrict__ vb,
             int M, int N, int K)
{
  __shared__ __bf16 As[128 * 32];
  __shared__ __bf16 Bs[128 * 32];
  const int tid  = threadIdx.x;
  const int wave = tid >> 6, lane = tid & 63;
  const int g = lane >> 4, r = lane & 15;
  const int ntiles = N >> 7;
  const int m0 = (blockIdx.x / ntiles) << 7;
  const int n0 = (blockIdx.x % ntiles) << 7;
  const int wr = wave >> 1, wc = wave & 1;

  f32x4 acc[4][4] = {};

  // staging source: chunk c = issue*4 + wave covers rows [c*16, c*16+16)
  const char* gA = (const char*)A + ((size_t)(m0 + (wave << 4) + (lane >> 2)) * K + (lane & 3) * 8) * 2;
  const char* gB = (const char*)Bt + ((size_t)(n0 + (wave << 4) + (lane >> 2)) * K + (lane & 3) * 8) * 2;
  char* lA = (char*)As + wave * 1024;
  char* lB = (char*)Bs + wave * 1024;
  const size_t rowskip = (size_t)64 * K * 2;

  for (int k0 = 0; k0 < K; k0 += 32) {
    __syncthreads();                       // prev compute done before overwrite
    gload_lds16(gA, lA);
    gload_lds16(gA + rowskip, lA + 4096);
    gload_lds16(gB, lB);
    gload_lds16(gB + rowskip, lB + 4096);
    gA += 64; gB += 64;                    // advance 32 bf16 in k
    __syncthreads();                       // waits vmcnt(0): LDS data ready

    bf16x8 af[4], bfr[4];
#pragma unroll
    for (int mi = 0; mi < 4; ++mi)
      af[mi] = *(const bf16x8*)((const char*)As + ((wr * 64 + mi * 16 + r) * 32 + g * 8) * 2);
#pragma unroll
    for (int ni = 0; ni < 4; ++ni)
      bfr[ni] = *(const bf16x8*)((const char*)Bs + ((wc * 64 + ni * 16 + r) * 32 + g * 8) * 2);
#pragma unroll
    for (int mi = 0; mi < 4; ++mi)
#pragma unroll
      for (int ni = 0; ni < 4; ++ni)
        acc[mi][ni] = MFMA16(af[mi], bfr[ni], acc[mi][ni]);
  }

  if (EPI == 1) {
#pragma unroll
    for (int mi = 0; mi < 4; ++mi) {
      int row = m0 + wr * 64 + mi * 16 + g * 4;
#pragma unroll
      for (int ni = 0; ni < 4; ++ni) {
        int col = n0 + wc * 64 + ni * 16 + r;
        float bv = bvec[col];
#pragma unroll
        for (int j = 0; j < 4; ++j)
          outp[(size_t)(row + j) * N + col] = acc[mi][ni][j] + bv;
      }
    }
  } else {
    // whole block maps to exactly one of q/k/v (n0 is 128-aligned, 512 splits)
    __bf16* dst; float scl;
    const int which = n0 >> 9;
    if (which == 0)      { dst = qb; scl = 0.17677669529663687f; }
    else if (which == 1) { dst = kb; scl = 1.0f; }
    else                 { dst = vb; scl = 1.0f; }
#pragma unroll
    for (int mi = 0; mi < 4; ++mi) {
#pragma unroll
      for (int ni = 0; ni < 4; ++ni) {
        int n = n0 + wc * 64 + ni * 16 + r;
        float bv = bvec[n];
        int nl = n & 511;
        int h = nl >> 5, d = nl & 31;
#pragma unroll
        for (int j = 0; j < 4; ++j) {
          int m = m0 + wr * 64 + mi * 16 + g * 4 + j;
          int bb = m / 49, t = m - bb * 49;
          float val = (acc[mi][ni][j] + bv) * scl;
          dst[(((size_t)bb * 16 + h) * 49 + t) * 32 + d] = (__bf16)val;
        }
      }
    }
  }
}

// ---------------------------------------------------------------------------
// Attention: one wave per (b,h). 49 padded to 64. S=QK^T (q pre-scaled),
// +bias+mask, wave-parallel softmax, P through swizzled LDS, PV, write bf16
// attn-out in [B,49,C] layout (C = h*32+d).
// ---------------------------------------------------------------------------
__global__ __launch_bounds__(64)
void attn_k(const __bf16* __restrict__ qb, const __bf16* __restrict__ kb,
            const __bf16* __restrict__ vb, const float* __restrict__ bias,
            const float* __restrict__ mask, __bf16* __restrict__ ao)
{
  __shared__ __bf16 Vt[32 * 64];   // [d][t], XOR-swizzled rows
  __shared__ __bf16 P[64 * 64];    // [row][t], XOR-swizzled rows
  const int bh = blockIdx.x;
  const int b = bh >> 4, h = bh & 15;
  const int lane = threadIdx.x;
  const int g = lane >> 4, r = lane & 15;
  const bf16x8 z8 = {};
  const f32x4 z4 = {};

  const __bf16* q = qb + (size_t)bh * 49 * 32;
  const __bf16* k = kb + (size_t)bh * 49 * 32;
  const __bf16* v = vb + (size_t)bh * 49 * 32;

  // zero Vt (pad columns t>=49 must be 0)
#pragma unroll
  for (int i = 0; i < 4; ++i) ((bf16x8*)Vt)[i * 64 + lane] = z8;

  // Q/K fragments straight from global (A: row=lane&15, k=8*(lane>>4)+j)
  bf16x8 qa[4], ka[4];
#pragma unroll
  for (int i = 0; i < 4; ++i) {
    int row = i * 16 + r;
    qa[i] = (row < 49) ? *(const bf16x8*)(q + row * 32 + g * 8) : z8;
    ka[i] = (row < 49) ? *(const bf16x8*)(k + row * 32 + g * 8) : z8;
  }
  __syncthreads();   // Vt zeroing complete before transposed writes

  // stage V^T into LDS (row d stride 128B -> XOR-swizzle bytes by (d&7)<<4)
#pragma unroll
  for (int i = 0; i < 4; ++i) {
    int idx = i * 64 + lane;
    int t = idx >> 2, d0 = (idx & 3) << 3;
    if (t < 49) {
      bf16x8 vv = *(const bf16x8*)(v + t * 32 + d0);
#pragma unroll
      for (int j = 0; j < 8; ++j) {
        int d = d0 + j;
        int byteo = d * 128 + ((t * 2) ^ ((d & 7) << 4));
        *(__bf16*)((char*)Vt + byteo) = vv[j];
      }
    }
  }

  // S = Q K^T   (16 MFMA, K=32)
  f32x4 s[4][4];
#pragma unroll
  for (int mi = 0; mi < 4; ++mi)
#pragma unroll
    for (int ni = 0; ni < 4; ++ni)
      s[mi][ni] = MFMA16(qa[mi], ka[ni], z4);

  const float* biash = bias + h * 2401;
  const float* maskb = mask + (size_t)b * 2401;

  // bias + mask + padding, then row softmax (row lives in one 16-lane group)
#pragma unroll
  for (int mi = 0; mi < 4; ++mi) {
#pragma unroll
    for (int j = 0; j < 4; ++j) {
      int row = mi * 16 + g * 4 + j;
#pragma unroll
      for (int ni = 0; ni < 4; ++ni) {
        int col = ni * 16 + r;
        float val;
        if (row < 49 && col < 49)
          val = s[mi][ni][j] + biash[row * 49 + col] + maskb[row * 49 + col];
        else
          val = -1e30f;
        s[mi][ni][j] = val;
      }
    }
    f32x4 m4 = max4(max4(s[mi][0], s[mi][1]), max4(s[mi][2], s[mi][3]));
#pragma unroll
    for (int dd = 1; dd < 16; dd <<= 1) {
      f32x4 t4;
#pragma unroll
      for (int j = 0; j < 4; ++j) t4[j] = __shfl_xor(m4[j], dd);
      m4 = max4(m4, t4);
    }
    f32x4 sum4 = {};
#pragma unroll
    for (int ni = 0; ni < 4; ++ni) {
#pragma unroll
      for (int j = 0; j < 4; ++j)
        s[mi][ni][j] = __expf(s[mi][ni][j] - m4[j]);
      sum4 += s[mi][ni];
    }
#pragma unroll
    for (int dd = 1; dd < 16; dd <<= 1) {
#pragma unroll
      for (int j = 0; j < 4; ++j) sum4[j] += __shfl_xor(sum4[j], dd);
    }
    f32x4 rinv;
#pragma unroll
    for (int j = 0; j < 4; ++j) rinv[j] = 1.0f / sum4[j];
    // normalized P -> LDS bf16 (swizzled)
#pragma unroll
    for (int ni = 0; ni < 4; ++ni) {
#pragma unroll
      for (int j = 0; j < 4; ++j) {
        int row = mi * 16 + g * 4 + j;
        int col = ni * 16 + r;
        int byteo = row * 128 + ((col * 2) ^ ((row & 7) << 4));
        *(__bf16*)((char*)P + byteo) = (__bf16)(s[mi][ni][j] * rinv[j]);
      }
    }
  }
  __syncthreads();

  // PV: out[64][32] = P[64][64] x V[64][32]
  bf16x8 pf[4][2], vf[2][2];
#pragma unroll
  for (int mi = 0; mi < 4; ++mi) {
    int row = mi * 16 + r;
#pragma unroll
    for (int kk = 0; kk < 2; ++kk)
      pf[mi][kk] = *(const bf16x8*)((char*)P + row * 128 + (((kk * 32 + g * 8) * 2) ^ ((row & 7) << 4)));
  }
#pragma unroll
  for (int ni = 0; ni < 2; ++ni) {
    int row = ni * 16 + r;   // = d
#pragma unroll
    for (int kk = 0; kk < 2; ++kk)
      vf[ni][kk] = *(const bf16x8*)((char*)Vt + row * 128 + (((kk * 32 + g * 8) * 2) ^ ((row & 7) << 4)));
  }
  f32x4 o[4][2] = {};
#pragma unroll
  for (int mi = 0; mi < 4; ++mi)
#pragma unroll
    for (int ni = 0; ni < 2; ++ni)
#pragma unroll
      for (int kk = 0; kk < 2; ++kk)
        o[mi][ni] = MFMA16(pf[mi][kk], vf[ni][kk], o[mi][ni]);

  // write attn-out bf16 [B,49,512] (c = h*32 + d)
  __bf16* aob = ao + (size_t)b * 49 * 512 + h * 32;
#pragma unroll
  for (int mi = 0; mi < 4; ++mi) {
#pragma unroll
    for (int j = 0; j < 4; ++j) {
      int row = mi * 16 + g * 4 + j;
      if (row < 49) {
#pragma unroll
        for (int ni = 0; ni < 2; ++ni) {
          int d = ni * 16 + r;
          aob[(size_t)row * 512 + d] = (__bf16)o[mi][ni][j];
        }
      }
    }
  }
}

// ---------------------------------------------------------------------------
extern "C" void kernel_launch(void* const* d_in, const int* in_sizes, int n_in,
                              void* d_out, int out_size, void* d_ws, size_t ws_size,
                              hipStream_t stream)
{
  const float* hs    = (const float*)d_in[0];
  const float* mask  = (const float*)d_in[1];
  const float* qkv_w = (const float*)d_in[2];
  const float* qkv_b = (const float*)d_in[3];
  const float* out_w = (const float*)d_in[4];
  const float* out_b = (const float*)d_in[5];
  const float* rpt   = (const float*)d_in[6];
  float* out = (float*)d_out;

  char* ws = (char*)d_ws;
  // layout (bytes): hsb/ao 102,760,448 | qb | kb | vb | qwb 1,572,864 | owb 524,288 | bias 153,664
  __bf16* hsb  = (__bf16*)(ws);                  // reused as attn-out after GEMM1
  __bf16* qb   = (__bf16*)(ws + 102760448);
  __bf16* kb   = (__bf16*)(ws + 205520896);
  __bf16* vb   = (__bf16*)(ws + 308281344);
  __bf16* qwb  = (__bf16*)(ws + 411041792);
  __bf16* owb  = (__bf16*)(ws + 412614656);
  float*  bias = (float*) (ws + 413138944);

  prep_k<<<4247, 256, 0, stream>>>(qkv_w, out_w, rpt, qwb, owb, bias);
  cast_k<<<2048, 256, 0, stream>>>(hs, hsb, 6422528);
  gemm_bt<0><<<9408, 256, 0, stream>>>(hsb, qwb, qkv_b, nullptr, qb, kb, vb,
                                       100352, 1536, 512);
  attn_k<<<32768, 64, 0, stream>>>(qb, kb, vb, bias, mask, hsb);
  gemm_bt<1><<<3136, 256, 0, stream>>>(hsb, owb, out_b, out, nullptr, nullptr, nullptr,
                                       100352, 512, 512);
}

// Round 2
// 551.544 us; speedup vs baseline: 1.2518x; 1.2518x over previous
//
#include <hip/hip_runtime.h>
#include <hip/hip_bf16.h>

typedef __attribute__((ext_vector_type(8))) __bf16 bf16x8;
typedef __attribute__((ext_vector_type(4))) __bf16 bf16x4;
typedef __attribute__((ext_vector_type(4))) float f32x4;

#define MFMA16(a,b,c) __builtin_amdgcn_mfma_f32_16x16x32_bf16(a,b,c,0,0,0)

__device__ __forceinline__ void gload_lds16(const void* g, void* l) {
  __builtin_amdgcn_global_load_lds(
      (const __attribute__((address_space(1))) void*)g,
      (__attribute__((address_space(3))) void*)l, 16, 0, 0);
}

__device__ __forceinline__ f32x4 max4(f32x4 a, f32x4 b) {
  f32x4 c;
  c[0] = fmaxf(a[0], b[0]); c[1] = fmaxf(a[1], b[1]);
  c[2] = fmaxf(a[2], b[2]); c[3] = fmaxf(a[3], b[3]);
  return c;
}

// ---------------------------------------------------------------------------
// prep: cast weights to bf16, build padded bf16 bias table [16][64][64]
// pad: col>=49 -> -30000 (softmax mask), row>=49 -> 0 (rows discarded)
// ---------------------------------------------------------------------------
__global__ void prep_k(const float* __restrict__ qkv_w, const float* __restrict__ out_w,
                       const float* __restrict__ rpt,
                       __bf16* __restrict__ qwb, __bf16* __restrict__ owb,
                       __bf16* __restrict__ biasb)
{
  int i = blockIdx.x * 256 + threadIdx.x;
  if (i < 786432) { qwb[i] = (__bf16)qkv_w[i]; return; }
  i -= 786432;
  if (i < 262144) { owb[i] = (__bf16)out_w[i]; return; }
  i -= 262144;
  if (i < 65536) {
    int hh = i >> 12, qc = i & 4095, qq = qc >> 6, c = qc & 63;
    __bf16 val;
    if (c >= 49)      val = (__bf16)(-30000.0f);
    else if (qq >= 49) val = (__bf16)(0.0f);
    else {
      int dh = qq / 7 - c / 7 + 6;
      int dw = qq % 7 - c % 7 + 6;
      val = (__bf16)rpt[(dh * 13 + dw) * 16 + hh];
    }
    biasb[i] = val;
  }
}

// ---------------------------------------------------------------------------
// cast hidden_states f32 -> bf16 (8 elems/thread)
// ---------------------------------------------------------------------------
__global__ void cast_k(const float* __restrict__ in, __bf16* __restrict__ outb, int n8)
{
  int i = blockIdx.x * blockDim.x + threadIdx.x;
  int stride = gridDim.x * blockDim.x;
  for (; i < n8; i += stride) {
    const float4* p = (const float4*)in + (size_t)i * 2;
    float4 x = p[0], y = p[1];
    bf16x8 o;
    o[0] = (__bf16)x.x; o[1] = (__bf16)x.y; o[2] = (__bf16)x.z; o[3] = (__bf16)x.w;
    o[4] = (__bf16)y.x; o[5] = (__bf16)y.y; o[6] = (__bf16)y.z; o[7] = (__bf16)y.w;
    ((bf16x8*)outb)[i] = o;
  }
}

// ---------------------------------------------------------------------------
// GEMM  C[m,n] = sum_k A[m,k] * Bt[n,k]   (A: [M][K] bf16, Bt: [N][K] bf16)
// 128x128 tile, BK=32, 4 waves of 64x64, global_load_lds staging.
// EPI 0: qkv scatter epilogue (+bias, q scaled, write bf16 [B,H,49,32])
// EPI 1: plain epilogue (+bias, fp32 out [M][N])
// ---------------------------------------------------------------------------
template<int EPI>
__global__ __launch_bounds__(256, 3)
void gemm_bt(const __bf16* __restrict__ A, const __bf16* __restrict__ Bt,
             const float* __restrict__ bvec, float* __restrict__ outp,
             __bf16* __restrict__ qb, __bf16* __restrict__ kb, __bf16* __restrict__ vb,
             int M, int N, int K)
{
  __shared__ __bf16 As[128 * 32];
  __shared__ __bf16 Bs[128 * 32];
  const int tid  = threadIdx.x;
  const int wave = tid >> 6, lane = tid & 63;
  const int g = lane >> 4, r = lane & 15;
  const int ntiles = N >> 7;
  const int m0 = (blockIdx.x / ntiles) << 7;
  const int n0 = (blockIdx.x % ntiles) << 7;
  const int wr = wave >> 1, wc = wave & 1;

  f32x4 acc[4][4] = {};

  const char* gA = (const char*)A + ((size_t)(m0 + (wave << 4) + (lane >> 2)) * K + (lane & 3) * 8) * 2;
  const char* gB = (const char*)Bt + ((size_t)(n0 + (wave << 4) + (lane >> 2)) * K + (lane & 3) * 8) * 2;
  char* lA = (char*)As + wave * 1024;
  char* lB = (char*)Bs + wave * 1024;
  const size_t rowskip = (size_t)64 * K * 2;

  for (int k0 = 0; k0 < K; k0 += 32) {
    __syncthreads();
    gload_lds16(gA, lA);
    gload_lds16(gA + rowskip, lA + 4096);
    gload_lds16(gB, lB);
    gload_lds16(gB + rowskip, lB + 4096);
    gA += 64; gB += 64;
    __syncthreads();

    bf16x8 af[4], bfr[4];
#pragma unroll
    for (int mi = 0; mi < 4; ++mi)
      af[mi] = *(const bf16x8*)((const char*)As + ((wr * 64 + mi * 16 + r) * 32 + g * 8) * 2);
#pragma unroll
    for (int ni = 0; ni < 4; ++ni)
      bfr[ni] = *(const bf16x8*)((const char*)Bs + ((wc * 64 + ni * 16 + r) * 32 + g * 8) * 2);
#pragma unroll
    for (int mi = 0; mi < 4; ++mi)
#pragma unroll
      for (int ni = 0; ni < 4; ++ni)
        acc[mi][ni] = MFMA16(af[mi], bfr[ni], acc[mi][ni]);
  }

  if (EPI == 1) {
#pragma unroll
    for (int mi = 0; mi < 4; ++mi) {
      int row = m0 + wr * 64 + mi * 16 + g * 4;
#pragma unroll
      for (int ni = 0; ni < 4; ++ni) {
        int col = n0 + wc * 64 + ni * 16 + r;
        float bv = bvec[col];
#pragma unroll
        for (int j = 0; j < 4; ++j)
          outp[(size_t)(row + j) * N + col] = acc[mi][ni][j] + bv;
      }
    }
  } else {
    __bf16* dst; float scl;
    const int which = n0 >> 9;
    if (which == 0)      { dst = qb; scl = 0.17677669529663687f; }
    else if (which == 1) { dst = kb; scl = 1.0f; }
    else                 { dst = vb; scl = 1.0f; }
#pragma unroll
    for (int mi = 0; mi < 4; ++mi) {
#pragma unroll
      for (int ni = 0; ni < 4; ++ni) {
        int n = n0 + wc * 64 + ni * 16 + r;
        float bv = bvec[n];
        int nl = n & 511;
        int hh = nl >> 5, d = nl & 31;
#pragma unroll
        for (int j = 0; j < 4; ++j) {
          int m = m0 + wr * 64 + mi * 16 + g * 4 + j;
          int bb = m / 49, t = m - bb * 49;
          float val = (acc[mi][ni][j] + bv) * scl;
          dst[(((size_t)bb * 16 + hh) * 49 + t) * 32 + d] = (__bf16)val;
        }
      }
    }
  }
}

// ---------------------------------------------------------------------------
// Attention: 4 waves/block = 4 heads of one b. Swapped QK^T (mfma(K,Q)) so
// the score column index lives in registers -> vector bias (bf16x4, global,
// padded table) and mask (float4 from swizzled LDS). Softmax row-reduce is
// 2 shfl_xor. Per-wave P chunk (16x64) through swizzled LDS per q-block.
// ---------------------------------------------------------------------------
__global__ __launch_bounds__(256, 4)
void attn_k(const __bf16* __restrict__ qb, const __bf16* __restrict__ kb,
            const __bf16* __restrict__ vb, const __bf16* __restrict__ bias_p,
            const float* __restrict__ mask, __bf16* __restrict__ ao)
{
  __shared__ float maskl[64 * 64];        // 16 KB, padded+swizzled
  __shared__ __bf16 Vt[4][32 * 64];       // 16 KB, per-wave V^T, swizzled
  __shared__ __bf16 Pl[4][16 * 64];       // 8 KB, per-wave P chunk, swizzled
  const int tid = threadIdx.x, wave = tid >> 6, lane = tid & 63;
  const int g = lane >> 4, r = lane & 15;
  const int b = blockIdx.x >> 2, hg = blockIdx.x & 3;
  const int h = hg * 4 + wave;
  const size_t bh = (size_t)b * 16 + h;
  const __bf16* q = qb + bh * 1568;
  const __bf16* k = kb + bh * 1568;
  const __bf16* v = vb + bh * 1568;
  const bf16x8 z8 = {};
  const f32x4 z4 = {};

  // zero own Vt (pad rows m>=49 must read 0)
  bf16x8* vtz = (bf16x8*)Vt[wave];
#pragma unroll
  for (int i = 0; i < 4; ++i) vtz[i * 64 + lane] = z8;

  // cooperative mask stage (pad 0, XOR-swizzled f32 columns)
  const float* mb = mask + (size_t)b * 2401;
#pragma unroll
  for (int i = 0; i < 16; ++i) {
    int idx = i * 256 + tid;
    int qq = idx >> 6, c = idx & 63;
    float mv = (qq < 49 && c < 49) ? mb[qq * 49 + c] : 0.0f;
    maskl[qq * 64 + (c ^ ((qq & 7) << 2))] = mv;
  }

  // K (A-operand) and Q (B-operand) fragments, rows >= 49 zeroed
  bf16x8 kf[4], qf[4];
#pragma unroll
  for (int i = 0; i < 4; ++i) {
    int row = i * 16 + r;
    kf[i] = (row < 49) ? *(const bf16x8*)(k + row * 32 + g * 8) : z8;
    qf[i] = (row < 49) ? *(const bf16x8*)(q + row * 32 + g * 8) : z8;
  }

  __syncthreads();   // mask staged; Vt zeros committed

  // stage V^T into own Vt (row d, byte-swizzled)
  char* vt = (char*)Vt[wave];
#pragma unroll
  for (int i = 0; i < 4; ++i) {
    int idx = i * 64 + lane;
    int t = idx >> 2, d0 = (idx & 3) << 3;
    if (t < 49) {
      bf16x8 vv = *(const bf16x8*)(v + t * 32 + d0);
#pragma unroll
      for (int j = 0; j < 8; ++j) {
        int d = d0 + j;
        *(__bf16*)(vt + d * 128 + ((t * 2) ^ ((d & 7) << 4))) = vv[j];
      }
    }
  }

  // V fragments (B-operand for PV), reused across all q-blocks
  bf16x8 vf[2][2];
#pragma unroll
  for (int di = 0; di < 2; ++di) {
    int row = di * 16 + r;
#pragma unroll
    for (int t = 0; t < 2; ++t)
      vf[di][t] = *(const bf16x8*)(vt + row * 128 + (((t * 32 + g * 8) * 2) ^ ((row & 7) << 4)));
  }

  const __bf16* bp = bias_p + h * 4096;
  char* pw = (char*)Pl[wave];
  __bf16* aob = ao + (size_t)b * 25088 + h * 32;
  const int swz = (r & 7) << 4;          // byte swizzle, P rows indexed by r
  const int mswz = (r & 7) << 2;         // f32 swizzle for mask reads

#pragma unroll
  for (int qi = 0; qi < 4; ++qi) {
    // S^T: lane holds S[qrow = 16qi + r][c = 16mi + 4g + jj]
    f32x4 s[4];
#pragma unroll
    for (int mi = 0; mi < 4; ++mi) s[mi] = MFMA16(kf[mi], qf[qi], z4);

    const int qrow = qi * 16 + r;
#pragma unroll
    for (int mi = 0; mi < 4; ++mi) {
      int c0 = mi * 16 + g * 4;
      bf16x4 b4 = *(const bf16x4*)(bp + qrow * 64 + c0);
      f32x4 m4 = *(const f32x4*)(maskl + qrow * 64 + (c0 ^ mswz));
#pragma unroll
      for (int jj = 0; jj < 4; ++jj)
        s[mi][jj] += (float)b4[jj] + m4[jj];
    }
    // row max: 16 in-lane + cross-group (g lives at lane stride 16)
    f32x4 a = max4(max4(s[0], s[1]), max4(s[2], s[3]));
    float mx = fmaxf(fmaxf(a[0], a[1]), fmaxf(a[2], a[3]));
    mx = fmaxf(mx, __shfl_xor(mx, 16));
    mx = fmaxf(mx, __shfl_xor(mx, 32));
    float sum = 0.0f;
#pragma unroll
    for (int mi = 0; mi < 4; ++mi) {
#pragma unroll
      for (int jj = 0; jj < 4; ++jj) {
        float e = __expf(s[mi][jj] - mx);
        s[mi][jj] = e;
        sum += e;
      }
    }
    sum += __shfl_xor(sum, 16);
    sum += __shfl_xor(sum, 32);
    const float rinv = 1.0f / sum;

    // normalized P chunk -> LDS (rows = r, swizzled), then A-frags back
#pragma unroll
    for (int mi = 0; mi < 4; ++mi) {
      bf16x4 w;
#pragma unroll
      for (int jj = 0; jj < 4; ++jj) w[jj] = (__bf16)(s[mi][jj] * rinv);
      *(bf16x4*)(pw + r * 128 + (((mi * 16 + g * 4) * 2) ^ swz)) = w;
    }
    bf16x8 pa0 = *(const bf16x8*)(pw + r * 128 + ((g * 16) ^ swz));
    bf16x8 pa1 = *(const bf16x8*)(pw + r * 128 + ((64 + g * 16) ^ swz));

#pragma unroll
    for (int di = 0; di < 2; ++di) {
      f32x4 o = MFMA16(pa0, vf[di][0], z4);
      o = MFMA16(pa1, vf[di][1], o);
#pragma unroll
      for (int jj = 0; jj < 4; ++jj) {
        int qq = qi * 16 + g * 4 + jj;
        if (qq < 49)
          aob[(size_t)qq * 512 + di * 16 + r] = (__bf16)o[jj];
      }
    }
  }
}

// ---------------------------------------------------------------------------
extern "C" void kernel_launch(void* const* d_in, const int* in_sizes, int n_in,
                              void* d_out, int out_size, void* d_ws, size_t ws_size,
                              hipStream_t stream)
{
  const float* hs    = (const float*)d_in[0];
  const float* mask  = (const float*)d_in[1];
  const float* qkv_w = (const float*)d_in[2];
  const float* qkv_b = (const float*)d_in[3];
  const float* out_w = (const float*)d_in[4];
  const float* out_b = (const float*)d_in[5];
  const float* rpt   = (const float*)d_in[6];
  float* out = (float*)d_out;

  char* ws = (char*)d_ws;
  __bf16* hsb  = (__bf16*)(ws);                  // reused as attn-out after GEMM1
  __bf16* qb   = (__bf16*)(ws + 102760448);
  __bf16* kb   = (__bf16*)(ws + 205520896);
  __bf16* vb   = (__bf16*)(ws + 308281344);
  __bf16* qwb  = (__bf16*)(ws + 411041792);
  __bf16* owb  = (__bf16*)(ws + 412614656);
  __bf16* biasb= (__bf16*)(ws + 413138944);      // [16][64][64] bf16

  prep_k<<<4352, 256, 0, stream>>>(qkv_w, out_w, rpt, qwb, owb, biasb);
  cast_k<<<2048, 256, 0, stream>>>(hs, hsb, 6422528);
  gemm_bt<0><<<9408, 256, 0, stream>>>(hsb, qwb, qkv_b, nullptr, qb, kb, vb,
                                       100352, 1536, 512);
  attn_k<<<8192, 256, 0, stream>>>(qb, kb, vb, biasb, mask, hsb);
  gemm_bt<1><<<3136, 256, 0, stream>>>(hsb, owb, out_b, out, nullptr, nullptr, nullptr,
                                       100352, 512, 512);
}

// Round 3
// 526.821 us; speedup vs baseline: 1.3106x; 1.0469x over previous
//
#include <hip/hip_runtime.h>
#include <hip/hip_bf16.h>

typedef __attribute__((ext_vector_type(8))) __bf16 bf16x8;
typedef __attribute__((ext_vector_type(4))) __bf16 bf16x4;
typedef __attribute__((ext_vector_type(4))) float f32x4;

#define MFMA16(a,b,c) __builtin_amdgcn_mfma_f32_16x16x32_bf16(a,b,c,0,0,0)

__device__ __forceinline__ void gload_lds16(const void* g, void* l) {
  __builtin_amdgcn_global_load_lds(
      (const __attribute__((address_space(1))) void*)g,
      (__attribute__((address_space(3))) void*)l, 16, 0, 0);
}

__device__ __forceinline__ f32x4 max4(f32x4 a, f32x4 b) {
  f32x4 c;
  c[0] = fmaxf(a[0], b[0]); c[1] = fmaxf(a[1], b[1]);
  c[2] = fmaxf(a[2], b[2]); c[3] = fmaxf(a[3], b[3]);
  return c;
}

// ---------------------------------------------------------------------------
// prep: cast weights to bf16, build padded bf16 bias table [16][64][64]
// ---------------------------------------------------------------------------
__global__ void prep_k(const float* __restrict__ qkv_w, const float* __restrict__ out_w,
                       const float* __restrict__ rpt,
                       __bf16* __restrict__ qwb, __bf16* __restrict__ owb,
                       __bf16* __restrict__ biasb)
{
  int i = blockIdx.x * 256 + threadIdx.x;
  if (i < 786432) { qwb[i] = (__bf16)qkv_w[i]; return; }
  i -= 786432;
  if (i < 262144) { owb[i] = (__bf16)out_w[i]; return; }
  i -= 262144;
  if (i < 65536) {
    int hh = i >> 12, qc = i & 4095, qq = qc >> 6, c = qc & 63;
    __bf16 val;
    if (c >= 49)      val = (__bf16)(-30000.0f);
    else if (qq >= 49) val = (__bf16)(0.0f);
    else {
      int dh = qq / 7 - c / 7 + 6;
      int dw = qq % 7 - c % 7 + 6;
      val = (__bf16)rpt[(dh * 13 + dw) * 16 + hh];
    }
    biasb[i] = val;
  }
}

// ---------------------------------------------------------------------------
// cast hidden_states f32 -> bf16 (8 elems/thread)
// ---------------------------------------------------------------------------
__global__ void cast_k(const float* __restrict__ in, __bf16* __restrict__ outb, int n8)
{
  int i = blockIdx.x * blockDim.x + threadIdx.x;
  int stride = gridDim.x * blockDim.x;
  for (; i < n8; i += stride) {
    const float4* p = (const float4*)in + (size_t)i * 2;
    float4 x = p[0], y = p[1];
    bf16x8 o;
    o[0] = (__bf16)x.x; o[1] = (__bf16)x.y; o[2] = (__bf16)x.z; o[3] = (__bf16)x.w;
    o[4] = (__bf16)y.x; o[5] = (__bf16)y.y; o[6] = (__bf16)y.z; o[7] = (__bf16)y.w;
    ((bf16x8*)outb)[i] = o;
  }
}

// ---------------------------------------------------------------------------
// 8-phase 256x256 GEMM (T2+T3+T4+T5).  C[m,n] = sum_k A[m,k]*Bt[n,k].
// BK=64, 8 waves (2Mx4N), per-wave out 128x64, LDS 2x(32K A + 32K B) dbuf.
// Swizzle: logical chunk ch (16B units within 128B row) stored at ch^(row&7);
// applied via pre-swizzled GLOBAL source (linear gload_lds dest, rule 21) and
// on the ds_read address. K=512 fixed (8 K-tiles), counted vmcnt(8) at top,
// tile kt+2 restaged into buf[kt&1] in phase 3 (all reads done at phase-2 end).
// ---------------------------------------------------------------------------
template<int EPI>
__global__ __launch_bounds__(512, 2)
void gemm8p(const __bf16* __restrict__ A, const __bf16* __restrict__ Bt,
            const float* __restrict__ bvec, float* __restrict__ outp,
            __bf16* __restrict__ qb, __bf16* __restrict__ kb, __bf16* __restrict__ vb,
            int N, int K)
{
  __shared__ __align__(16) char lds[131072];
  const int tid = threadIdx.x;
  const int wave = tid >> 6, lane = tid & 63;
  const int g = lane >> 4, r = lane & 15;
  const int l8 = lane >> 3, l7 = lane & 7;
  const int wr = wave >> 2, wc = wave & 3;

  const int ntiles = N >> 8;
  const int nper = gridDim.x >> 3;                       // grid % 8 == 0
  const int b2 = (blockIdx.x & 7) * nper + (blockIdx.x >> 3);  // XCD swizzle
  const int m0 = (b2 / ntiles) << 8;
  const int n0 = (b2 % ntiles) << 8;

  // staging source bases (per-thread, pre-swizzled in the chunk index)
  const __bf16* Ag = A + (size_t)(m0 + wave * 8 + l8) * K + (l7 ^ l8) * 8;
  const __bf16* Bg = Bt + (size_t)(n0 + wave * 8 + l8) * K + (l7 ^ l8) * 8;
  const size_t c64 = (size_t)64 * K;

  // ds_read bases: row*128 bytes, chunk ((kk*4+g)^(r&7))*16
  const int swz = r & 7;
  const int ch0 = (g ^ swz) << 4;
  const int ch1 = ((4 + g) ^ swz) << 4;
  const char* Ar = lds + (wr * 128 + r) * 128;
  const char* Br = lds + 32768 + (wc * 64 + r) * 128;

  f32x4 acc[8][4] = {};
  bf16x8 a[4][2], b[4][2];

  // prologue: stage tiles 0 and 1
#pragma unroll
  for (int c = 0; c < 4; ++c) {
    gload_lds16(Ag + c * c64, lds + wave * 1024 + c * 8192);
    gload_lds16(Bg + c * c64, lds + 32768 + wave * 1024 + c * 8192);
  }
#pragma unroll
  for (int c = 0; c < 4; ++c) {
    gload_lds16(Ag + 64 + c * c64, lds + 65536 + wave * 1024 + c * 8192);
    gload_lds16(Bg + 64 + c * c64, lds + 65536 + 32768 + wave * 1024 + c * 8192);
  }

#pragma unroll 1
  for (int kt = 0; kt < 8; ++kt) {
    const int cur = (kt & 1) << 16;
    const char* Ab = Ar + cur;
    const char* Bb = Br + cur;
    if (kt == 7) asm volatile("s_waitcnt vmcnt(0)" ::: "memory");
    else         asm volatile("s_waitcnt vmcnt(8)" ::: "memory");
    __builtin_amdgcn_s_barrier();

    // ---- phase 0: read A[0..3], B[0..1]; MFMA quad (m-lo, n-lo)
#pragma unroll
    for (int mi = 0; mi < 4; ++mi) {
      a[mi][0] = *(const bf16x8*)(Ab + mi * 2048 + ch0);
      a[mi][1] = *(const bf16x8*)(Ab + mi * 2048 + ch1);
    }
#pragma unroll
    for (int ni = 0; ni < 2; ++ni) {
      b[ni][0] = *(const bf16x8*)(Bb + ni * 2048 + ch0);
      b[ni][1] = *(const bf16x8*)(Bb + ni * 2048 + ch1);
    }
    __builtin_amdgcn_s_barrier();
    asm volatile("s_waitcnt lgkmcnt(0)" ::: "memory");
    __builtin_amdgcn_sched_barrier(0);
    __builtin_amdgcn_s_setprio(1);
#pragma unroll
    for (int mi = 0; mi < 4; ++mi)
#pragma unroll
      for (int ni = 0; ni < 2; ++ni) {
        acc[mi][ni] = MFMA16(a[mi][0], b[ni][0], acc[mi][ni]);
        acc[mi][ni] = MFMA16(a[mi][1], b[ni][1], acc[mi][ni]);
      }
    __builtin_amdgcn_s_setprio(0);
    __builtin_amdgcn_s_barrier();

    // ---- phase 1: read B[2..3]; MFMA quad (m-lo, n-hi)
#pragma unroll
    for (int ni = 2; ni < 4; ++ni) {
      b[ni][0] = *(const bf16x8*)(Bb + ni * 2048 + ch0);
      b[ni][1] = *(const bf16x8*)(Bb + ni * 2048 + ch1);
    }
    __builtin_amdgcn_s_barrier();
    asm volatile("s_waitcnt lgkmcnt(0)" ::: "memory");
    __builtin_amdgcn_sched_barrier(0);
    __builtin_amdgcn_s_setprio(1);
#pragma unroll
    for (int mi = 0; mi < 4; ++mi)
#pragma unroll
      for (int ni = 2; ni < 4; ++ni) {
        acc[mi][ni] = MFMA16(a[mi][0], b[ni][0], acc[mi][ni]);
        acc[mi][ni] = MFMA16(a[mi][1], b[ni][1], acc[mi][ni]);
      }
    __builtin_amdgcn_s_setprio(0);
    __builtin_amdgcn_s_barrier();

    // ---- phase 2: read A[4..7]; MFMA quad (m-hi, n-hi)
#pragma unroll
    for (int mi = 0; mi < 4; ++mi) {
      a[mi][0] = *(const bf16x8*)(Ab + (4 + mi) * 2048 + ch0);
      a[mi][1] = *(const bf16x8*)(Ab + (4 + mi) * 2048 + ch1);
    }
    __builtin_amdgcn_s_barrier();
    asm volatile("s_waitcnt lgkmcnt(0)" ::: "memory");
    __builtin_amdgcn_sched_barrier(0);
    __builtin_amdgcn_s_setprio(1);
#pragma unroll
    for (int mi = 0; mi < 4; ++mi)
#pragma unroll
      for (int ni = 2; ni < 4; ++ni) {
        acc[4 + mi][ni] = MFMA16(a[mi][0], b[ni][0], acc[4 + mi][ni]);
        acc[4 + mi][ni] = MFMA16(a[mi][1], b[ni][1], acc[4 + mi][ni]);
      }
    __builtin_amdgcn_s_setprio(0);
    __builtin_amdgcn_s_barrier();

    // ---- phase 3: restage tile kt+2 into buf[kt&1] (reads of it all done),
    //               MFMA quad (m-hi, n-lo)
    if (kt < 6) {
      const __bf16* Agk = Ag + (kt + 2) * 64;
      const __bf16* Bgk = Bt == A ? Agk : Bg + (kt + 2) * 64;  // keep simple; Bgk below
      (void)Bgk;
      char* Al = lds + cur + wave * 1024;
      char* Bl = lds + cur + 32768 + wave * 1024;
      const __bf16* Bgk2 = Bg + (kt + 2) * 64;
#pragma unroll
      for (int c = 0; c < 4; ++c) {
        gload_lds16(Agk + c * c64, Al + c * 8192);
        gload_lds16(Bgk2 + c * c64, Bl + c * 8192);
      }
    }
    __builtin_amdgcn_s_setprio(1);
#pragma unroll
    for (int mi = 0; mi < 4; ++mi)
#pragma unroll
      for (int ni = 0; ni < 2; ++ni) {
        acc[4 + mi][ni] = MFMA16(a[mi][0], b[ni][0], acc[4 + mi][ni]);
        acc[4 + mi][ni] = MFMA16(a[mi][1], b[ni][1], acc[4 + mi][ni]);
      }
    __builtin_amdgcn_s_setprio(0);
    __builtin_amdgcn_s_barrier();
  }

  if (EPI == 1) {
#pragma unroll
    for (int mi = 0; mi < 8; ++mi) {
      int row = m0 + wr * 128 + mi * 16 + g * 4;
#pragma unroll
      for (int ni = 0; ni < 4; ++ni) {
        int col = n0 + wc * 64 + ni * 16 + r;
        float bv = bvec[col];
#pragma unroll
        for (int j = 0; j < 4; ++j)
          outp[(size_t)(row + j) * N + col] = acc[mi][ni][j] + bv;
      }
    }
  } else {
    __bf16* dst; float scl;
    const int which = n0 >> 9;
    if (which == 0)      { dst = qb; scl = 0.17677669529663687f; }
    else if (which == 1) { dst = kb; scl = 1.0f; }
    else                 { dst = vb; scl = 1.0f; }
    float bv[4];
#pragma unroll
    for (int ni = 0; ni < 4; ++ni) bv[ni] = bvec[n0 + wc * 64 + ni * 16 + r];
#pragma unroll
    for (int mi = 0; mi < 8; ++mi) {
#pragma unroll
      for (int j = 0; j < 4; ++j) {
        int m = m0 + wr * 128 + mi * 16 + g * 4 + j;
        int bb = m / 49, t = m - bb * 49;
        __bf16* drow = dst + ((size_t)bb * 16) * 1568 + t * 32;
#pragma unroll
        for (int ni = 0; ni < 4; ++ni) {
          int nl = (n0 + wc * 64 + ni * 16 + r) & 511;
          int hh = nl >> 5, d = nl & 31;
          float val = (acc[mi][ni][j] + bv[ni]) * scl;
          drow[(size_t)hh * 1568 + d] = (__bf16)val;
        }
      }
    }
  }
}

// ---------------------------------------------------------------------------
// Attention: 4 waves/block = 4 heads of one b (unchanged from round 2).
// ---------------------------------------------------------------------------
__global__ __launch_bounds__(256, 4)
void attn_k(const __bf16* __restrict__ qb, const __bf16* __restrict__ kb,
            const __bf16* __restrict__ vb, const __bf16* __restrict__ bias_p,
            const float* __restrict__ mask, __bf16* __restrict__ ao)
{
  __shared__ float maskl[64 * 64];
  __shared__ __bf16 Vt[4][32 * 64];
  __shared__ __bf16 Pl[4][16 * 64];
  const int tid = threadIdx.x, wave = tid >> 6, lane = tid & 63;
  const int g = lane >> 4, r = lane & 15;
  const int b = blockIdx.x >> 2, hg = blockIdx.x & 3;
  const int h = hg * 4 + wave;
  const size_t bh = (size_t)b * 16 + h;
  const __bf16* q = qb + bh * 1568;
  const __bf16* k = kb + bh * 1568;
  const __bf16* v = vb + bh * 1568;
  const bf16x8 z8 = {};
  const f32x4 z4 = {};

  bf16x8* vtz = (bf16x8*)Vt[wave];
#pragma unroll
  for (int i = 0; i < 4; ++i) vtz[i * 64 + lane] = z8;

  const float* mb = mask + (size_t)b * 2401;
#pragma unroll
  for (int i = 0; i < 16; ++i) {
    int idx = i * 256 + tid;
    int qq = idx >> 6, c = idx & 63;
    float mv = (qq < 49 && c < 49) ? mb[qq * 49 + c] : 0.0f;
    maskl[qq * 64 + (c ^ ((qq & 7) << 2))] = mv;
  }

  bf16x8 kf[4], qf[4];
#pragma unroll
  for (int i = 0; i < 4; ++i) {
    int row = i * 16 + r;
    kf[i] = (row < 49) ? *(const bf16x8*)(k + row * 32 + g * 8) : z8;
    qf[i] = (row < 49) ? *(const bf16x8*)(q + row * 32 + g * 8) : z8;
  }

  __syncthreads();

  char* vt = (char*)Vt[wave];
#pragma unroll
  for (int i = 0; i < 4; ++i) {
    int idx = i * 64 + lane;
    int t = idx >> 2, d0 = (idx & 3) << 3;
    if (t < 49) {
      bf16x8 vv = *(const bf16x8*)(v + t * 32 + d0);
#pragma unroll
      for (int j = 0; j < 8; ++j) {
        int d = d0 + j;
        *(__bf16*)(vt + d * 128 + ((t * 2) ^ ((d & 7) << 4))) = vv[j];
      }
    }
  }

  bf16x8 vf[2][2];
#pragma unroll
  for (int di = 0; di < 2; ++di) {
    int row = di * 16 + r;
#pragma unroll
    for (int t = 0; t < 2; ++t)
      vf[di][t] = *(const bf16x8*)(vt + row * 128 + (((t * 32 + g * 8) * 2) ^ ((row & 7) << 4)));
  }

  const __bf16* bp = bias_p + h * 4096;
  char* pw = (char*)Pl[wave];
  __bf16* aob = ao + (size_t)b * 25088 + h * 32;
  const int swz = (r & 7) << 4;
  const int mswz = (r & 7) << 2;

#pragma unroll
  for (int qi = 0; qi < 4; ++qi) {
    f32x4 s[4];
#pragma unroll
    for (int mi = 0; mi < 4; ++mi) s[mi] = MFMA16(kf[mi], qf[qi], z4);

    const int qrow = qi * 16 + r;
#pragma unroll
    for (int mi = 0; mi < 4; ++mi) {
      int c0 = mi * 16 + g * 4;
      bf16x4 b4 = *(const bf16x4*)(bp + qrow * 64 + c0);
      f32x4 m4 = *(const f32x4*)(maskl + qrow * 64 + (c0 ^ mswz));
#pragma unroll
      for (int jj = 0; jj < 4; ++jj)
        s[mi][jj] += (float)b4[jj] + m4[jj];
    }
    f32x4 aa = max4(max4(s[0], s[1]), max4(s[2], s[3]));
    float mx = fmaxf(fmaxf(aa[0], aa[1]), fmaxf(aa[2], aa[3]));
    mx = fmaxf(mx, __shfl_xor(mx, 16));
    mx = fmaxf(mx, __shfl_xor(mx, 32));
    float sum = 0.0f;
#pragma unroll
    for (int mi = 0; mi < 4; ++mi) {
#pragma unroll
      for (int jj = 0; jj < 4; ++jj) {
        float e = __expf(s[mi][jj] - mx);
        s[mi][jj] = e;
        sum += e;
      }
    }
    sum += __shfl_xor(sum, 16);
    sum += __shfl_xor(sum, 32);
    const float rinv = 1.0f / sum;

#pragma unroll
    for (int mi = 0; mi < 4; ++mi) {
      bf16x4 w;
#pragma unroll
      for (int jj = 0; jj < 4; ++jj) w[jj] = (__bf16)(s[mi][jj] * rinv);
      *(bf16x4*)(pw + r * 128 + (((mi * 16 + g * 4) * 2) ^ swz)) = w;
    }
    bf16x8 pa0 = *(const bf16x8*)(pw + r * 128 + ((g * 16) ^ swz));
    bf16x8 pa1 = *(const bf16x8*)(pw + r * 128 + ((64 + g * 16) ^ swz));

#pragma unroll
    for (int di = 0; di < 2; ++di) {
      f32x4 o = MFMA16(pa0, vf[di][0], z4);
      o = MFMA16(pa1, vf[di][1], o);
#pragma unroll
      for (int jj = 0; jj < 4; ++jj) {
        int qq = qi * 16 + g * 4 + jj;
        if (qq < 49)
          aob[(size_t)qq * 512 + di * 16 + r] = (__bf16)o[jj];
      }
    }
  }
}

// ---------------------------------------------------------------------------
extern "C" void kernel_launch(void* const* d_in, const int* in_sizes, int n_in,
                              void* d_out, int out_size, void* d_ws, size_t ws_size,
                              hipStream_t stream)
{
  const float* hs    = (const float*)d_in[0];
  const float* mask  = (const float*)d_in[1];
  const float* qkv_w = (const float*)d_in[2];
  const float* qkv_b = (const float*)d_in[3];
  const float* out_w = (const float*)d_in[4];
  const float* out_b = (const float*)d_in[5];
  const float* rpt   = (const float*)d_in[6];
  float* out = (float*)d_out;

  char* ws = (char*)d_ws;
  __bf16* hsb  = (__bf16*)(ws);                  // reused as attn-out after GEMM1
  __bf16* qb   = (__bf16*)(ws + 102760448);
  __bf16* kb   = (__bf16*)(ws + 205520896);
  __bf16* vb   = (__bf16*)(ws + 308281344);
  __bf16* qwb  = (__bf16*)(ws + 411041792);
  __bf16* owb  = (__bf16*)(ws + 412614656);
  __bf16* biasb= (__bf16*)(ws + 413138944);      // [16][64][64] bf16

  prep_k<<<4352, 256, 0, stream>>>(qkv_w, out_w, rpt, qwb, owb, biasb);
  cast_k<<<2048, 256, 0, stream>>>(hs, hsb, 6422528);
  gemm8p<0><<<2352, 512, 0, stream>>>(hsb, qwb, qkv_b, nullptr, qb, kb, vb,
                                      1536, 512);
  attn_k<<<8192, 256, 0, stream>>>(qb, kb, vb, biasb, mask, hsb);
  gemm8p<1><<<784, 512, 0, stream>>>(hsb, owb, out_b, out, nullptr, nullptr, nullptr,
                                     512, 512);
}

// Round 5
// 523.264 us; speedup vs baseline: 1.3195x; 1.0068x over previous
//
#include <hip/hip_runtime.h>
#include <hip/hip_bf16.h>

typedef __attribute__((ext_vector_type(8))) __bf16 bf16x8;
typedef __attribute__((ext_vector_type(4))) __bf16 bf16x4;
typedef __attribute__((ext_vector_type(4))) float f32x4;

#define MFMA16(a,b,c) __builtin_amdgcn_mfma_f32_16x16x32_bf16(a,b,c,0,0,0)

__device__ __forceinline__ void gload_lds16(const void* g, void* l) {
  __builtin_amdgcn_global_load_lds(
      (const __attribute__((address_space(1))) void*)g,
      (__attribute__((address_space(3))) void*)l, 16, 0, 0);
}

__device__ __forceinline__ f32x4 max4(f32x4 a, f32x4 b) {
  f32x4 c;
  c[0] = fmaxf(a[0], b[0]); c[1] = fmaxf(a[1], b[1]);
  c[2] = fmaxf(a[2], b[2]); c[3] = fmaxf(a[3], b[3]);
  return c;
}

// ---------------------------------------------------------------------------
// prep: cast weights to bf16, build padded bf16 bias table [16][64][64]
// ---------------------------------------------------------------------------
__global__ void prep_k(const float* __restrict__ qkv_w, const float* __restrict__ out_w,
                       const float* __restrict__ rpt,
                       __bf16* __restrict__ qwb, __bf16* __restrict__ owb,
                       __bf16* __restrict__ biasb)
{
  int i = blockIdx.x * 256 + threadIdx.x;
  if (i < 786432) { qwb[i] = (__bf16)qkv_w[i]; return; }
  i -= 786432;
  if (i < 262144) { owb[i] = (__bf16)out_w[i]; return; }
  i -= 262144;
  if (i < 65536) {
    int hh = i >> 12, qc = i & 4095, qq = qc >> 6, c = qc & 63;
    __bf16 val;
    if (c >= 49)      val = (__bf16)(-30000.0f);
    else if (qq >= 49) val = (__bf16)(0.0f);
    else {
      int dh = qq / 7 - c / 7 + 6;
      int dw = qq % 7 - c % 7 + 6;
      val = (__bf16)rpt[(dh * 13 + dw) * 16 + hh];
    }
    biasb[i] = val;
  }
}

// ---------------------------------------------------------------------------
// cast hidden_states f32 -> bf16 (8 elems/thread)
// ---------------------------------------------------------------------------
__global__ void cast_k(const float* __restrict__ in, __bf16* __restrict__ outb, int n8)
{
  int i = blockIdx.x * blockDim.x + threadIdx.x;
  int stride = gridDim.x * blockDim.x;
  for (; i < n8; i += stride) {
    const float4* p = (const float4*)in + (size_t)i * 2;
    float4 x = p[0], y = p[1];
    bf16x8 o;
    o[0] = (__bf16)x.x; o[1] = (__bf16)x.y; o[2] = (__bf16)x.z; o[3] = (__bf16)x.w;
    o[4] = (__bf16)y.x; o[5] = (__bf16)y.y; o[6] = (__bf16)y.z; o[7] = (__bf16)y.w;
    ((bf16x8*)outb)[i] = o;
  }
}

// ---------------------------------------------------------------------------
// 8-phase 256x256 GEMM (T2+T3+T4+T5), v4: round-3 race-free structure
// (staging burst in phase 3, after all reads of buf[cur] completed at the
// phase-2 end barrier) with the sched_barrier(0) order-pins REMOVED (m141
// regression pattern; ds_reads are compiler-visible so rule 18 not needed).
// BK=64, 8 waves (2Mx4N), LDS 2x(32K A + 32K B) dbuf, XOR swizzle via
// pre-swizzled global source + swizzled ds_read (rule 21). K=512 (8 K-tiles),
// counted vmcnt(8) at tile top (2-deep prefetch, never 0 mid-loop).
// ---------------------------------------------------------------------------
template<int EPI>
__global__ __launch_bounds__(512, 2)
void gemm8p(const __bf16* __restrict__ A, const __bf16* __restrict__ Bt,
            const float* __restrict__ bvec, float* __restrict__ outp,
            __bf16* __restrict__ qb, __bf16* __restrict__ kb, __bf16* __restrict__ vb,
            int N, int K)
{
  __shared__ __align__(16) char lds[131072];
  const int tid = threadIdx.x;
  const int wave = tid >> 6, lane = tid & 63;
  const int g = lane >> 4, r = lane & 15;
  const int l8 = lane >> 3, l7 = lane & 7;
  const int wr = wave >> 2, wc = wave & 3;

  const int ntiles = N >> 8;
  const int nper = gridDim.x >> 3;                       // grid % 8 == 0
  const int b2 = (blockIdx.x & 7) * nper + (blockIdx.x >> 3);  // XCD swizzle
  const int m0 = (b2 / ntiles) << 8;
  const int n0 = (b2 % ntiles) << 8;

  // staging source bases (per-thread, pre-swizzled in the chunk index)
  const __bf16* Ag = A + (size_t)(m0 + wave * 8 + l8) * K + (l7 ^ l8) * 8;
  const __bf16* Bg = Bt + (size_t)(n0 + wave * 8 + l8) * K + (l7 ^ l8) * 8;
  const size_t c64 = (size_t)64 * K;

  // ds_read bases: row*128 bytes, chunk ((kk*4+g)^(r&7))*16
  const int swz = r & 7;
  const int ch0 = (g ^ swz) << 4;
  const int ch1 = ((4 + g) ^ swz) << 4;
  const char* Ar = lds + (wr * 128 + r) * 128;
  const char* Br = lds + 32768 + (wc * 64 + r) * 128;

  f32x4 acc[8][4] = {};
  bf16x8 a[4][2], b[4][2];

  // prologue: stage tiles 0 and 1
#pragma unroll
  for (int c = 0; c < 4; ++c) {
    gload_lds16(Ag + c * c64, lds + wave * 1024 + c * 8192);
    gload_lds16(Bg + c * c64, lds + 32768 + wave * 1024 + c * 8192);
  }
#pragma unroll
  for (int c = 0; c < 4; ++c) {
    gload_lds16(Ag + 64 + c * c64, lds + 65536 + wave * 1024 + c * 8192);
    gload_lds16(Bg + 64 + c * c64, lds + 65536 + 32768 + wave * 1024 + c * 8192);
  }

#pragma unroll 1
  for (int kt = 0; kt < 8; ++kt) {
    const int cur = (kt & 1) << 16;
    const char* Ab = Ar + cur;
    const char* Bb = Br + cur;
    if (kt == 7) asm volatile("s_waitcnt vmcnt(0)" ::: "memory");
    else         asm volatile("s_waitcnt vmcnt(8)" ::: "memory");
    __builtin_amdgcn_s_barrier();

    // ---- phase 0: read A[0..3], B[0..1]; MFMA quad (m-lo, n-lo)
#pragma unroll
    for (int mi = 0; mi < 4; ++mi) {
      a[mi][0] = *(const bf16x8*)(Ab + mi * 2048 + ch0);
      a[mi][1] = *(const bf16x8*)(Ab + mi * 2048 + ch1);
    }
#pragma unroll
    for (int ni = 0; ni < 2; ++ni) {
      b[ni][0] = *(const bf16x8*)(Bb + ni * 2048 + ch0);
      b[ni][1] = *(const bf16x8*)(Bb + ni * 2048 + ch1);
    }
    __builtin_amdgcn_s_barrier();
    asm volatile("s_waitcnt lgkmcnt(0)" ::: "memory");
    __builtin_amdgcn_s_setprio(1);
#pragma unroll
    for (int mi = 0; mi < 4; ++mi)
#pragma unroll
      for (int ni = 0; ni < 2; ++ni) {
        acc[mi][ni] = MFMA16(a[mi][0], b[ni][0], acc[mi][ni]);
        acc[mi][ni] = MFMA16(a[mi][1], b[ni][1], acc[mi][ni]);
      }
    __builtin_amdgcn_s_setprio(0);
    __builtin_amdgcn_s_barrier();

    // ---- phase 1: read B[2..3]; MFMA quad (m-lo, n-hi)
#pragma unroll
    for (int ni = 2; ni < 4; ++ni) {
      b[ni][0] = *(const bf16x8*)(Bb + ni * 2048 + ch0);
      b[ni][1] = *(const bf16x8*)(Bb + ni * 2048 + ch1);
    }
    __builtin_amdgcn_s_barrier();
    asm volatile("s_waitcnt lgkmcnt(0)" ::: "memory");
    __builtin_amdgcn_s_setprio(1);
#pragma unroll
    for (int mi = 0; mi < 4; ++mi)
#pragma unroll
      for (int ni = 2; ni < 4; ++ni) {
        acc[mi][ni] = MFMA16(a[mi][0], b[ni][0], acc[mi][ni]);
        acc[mi][ni] = MFMA16(a[mi][1], b[ni][1], acc[mi][ni]);
      }
    __builtin_amdgcn_s_setprio(0);
    __builtin_amdgcn_s_barrier();

    // ---- phase 2: read A[4..7]; MFMA quad (m-hi, n-hi)
#pragma unroll
    for (int mi = 0; mi < 4; ++mi) {
      a[mi][0] = *(const bf16x8*)(Ab + (4 + mi) * 2048 + ch0);
      a[mi][1] = *(const bf16x8*)(Ab + (4 + mi) * 2048 + ch1);
    }
    __builtin_amdgcn_s_barrier();
    asm volatile("s_waitcnt lgkmcnt(0)" ::: "memory");
    __builtin_amdgcn_s_setprio(1);
#pragma unroll
    for (int mi = 0; mi < 4; ++mi)
#pragma unroll
      for (int ni = 2; ni < 4; ++ni) {
        acc[4 + mi][ni] = MFMA16(a[mi][0], b[ni][0], acc[4 + mi][ni]);
        acc[4 + mi][ni] = MFMA16(a[mi][1], b[ni][1], acc[4 + mi][ni]);
      }
    __builtin_amdgcn_s_setprio(0);
    __builtin_amdgcn_s_barrier();

    // ---- phase 3: restage tile kt+2 into buf[kt&1] (all reads of it are
    //               complete at the phase-2 end barrier); MFMA (m-hi, n-lo)
    if (kt < 6) {
      const __bf16* Agk = Ag + (kt + 2) * 64;
      const __bf16* Bgk = Bg + (kt + 2) * 64;
      char* Al = lds + cur + wave * 1024;
      char* Bl = lds + cur + 32768 + wave * 1024;
#pragma unroll
      for (int c = 0; c < 4; ++c) {
        gload_lds16(Agk + c * c64, Al + c * 8192);
        gload_lds16(Bgk + c * c64, Bl + c * 8192);
      }
    }
    __builtin_amdgcn_s_setprio(1);
#pragma unroll
    for (int mi = 0; mi < 4; ++mi)
#pragma unroll
      for (int ni = 0; ni < 2; ++ni) {
        acc[4 + mi][ni] = MFMA16(a[mi][0], b[ni][0], acc[4 + mi][ni]);
        acc[4 + mi][ni] = MFMA16(a[mi][1], b[ni][1], acc[4 + mi][ni]);
      }
    __builtin_amdgcn_s_setprio(0);
    __builtin_amdgcn_s_barrier();
  }

  if (EPI == 1) {
#pragma unroll
    for (int mi = 0; mi < 8; ++mi) {
      int row = m0 + wr * 128 + mi * 16 + g * 4;
#pragma unroll
      for (int ni = 0; ni < 4; ++ni) {
        int col = n0 + wc * 64 + ni * 16 + r;
        float bv = bvec[col];
#pragma unroll
        for (int j = 0; j < 4; ++j)
          outp[(size_t)(row + j) * N + col] = acc[mi][ni][j] + bv;
      }
    }
  } else {
    __bf16* dst; float scl;
    const int which = n0 >> 9;
    if (which == 0)      { dst = qb; scl = 0.17677669529663687f; }
    else if (which == 1) { dst = kb; scl = 1.0f; }
    else                 { dst = vb; scl = 1.0f; }
    float bv[4];
#pragma unroll
    for (int ni = 0; ni < 4; ++ni) bv[ni] = bvec[n0 + wc * 64 + ni * 16 + r];
#pragma unroll
    for (int mi = 0; mi < 8; ++mi) {
#pragma unroll
      for (int j = 0; j < 4; ++j) {
        int m = m0 + wr * 128 + mi * 16 + g * 4 + j;
        int bb = m / 49, t = m - bb * 49;
        __bf16* drow = dst + ((size_t)bb * 16) * 1568 + t * 32;
#pragma unroll
        for (int ni = 0; ni < 4; ++ni) {
          int nl = (n0 + wc * 64 + ni * 16 + r) & 511;
          int hh = nl >> 5, d = nl & 31;
          float val = (acc[mi][ni][j] + bv[ni]) * scl;
          drow[(size_t)hh * 1568 + d] = (__bf16)val;
        }
      }
    }
  }
}

// ---------------------------------------------------------------------------
// Attention: 4 waves/block = 4 heads of one b (unchanged from round 2).
// ---------------------------------------------------------------------------
__global__ __launch_bounds__(256, 4)
void attn_k(const __bf16* __restrict__ qb, const __bf16* __restrict__ kb,
            const __bf16* __restrict__ vb, const __bf16* __restrict__ bias_p,
            const float* __restrict__ mask, __bf16* __restrict__ ao)
{
  __shared__ float maskl[64 * 64];
  __shared__ __bf16 Vt[4][32 * 64];
  __shared__ __bf16 Pl[4][16 * 64];
  const int tid = threadIdx.x, wave = tid >> 6, lane = tid & 63;
  const int g = lane >> 4, r = lane & 15;
  const int b = blockIdx.x >> 2, hg = blockIdx.x & 3;
  const int h = hg * 4 + wave;
  const size_t bh = (size_t)b * 16 + h;
  const __bf16* q = qb + bh * 1568;
  const __bf16* k = kb + bh * 1568;
  const __bf16* v = vb + bh * 1568;
  const bf16x8 z8 = {};
  const f32x4 z4 = {};

  bf16x8* vtz = (bf16x8*)Vt[wave];
#pragma unroll
  for (int i = 0; i < 4; ++i) vtz[i * 64 + lane] = z8;

  const float* mb = mask + (size_t)b * 2401;
#pragma unroll
  for (int i = 0; i < 16; ++i) {
    int idx = i * 256 + tid;
    int qq = idx >> 6, c = idx & 63;
    float mv = (qq < 49 && c < 49) ? mb[qq * 49 + c] : 0.0f;
    maskl[qq * 64 + (c ^ ((qq & 7) << 2))] = mv;
  }

  bf16x8 kf[4], qf[4];
#pragma unroll
  for (int i = 0; i < 4; ++i) {
    int row = i * 16 + r;
    kf[i] = (row < 49) ? *(const bf16x8*)(k + row * 32 + g * 8) : z8;
    qf[i] = (row < 49) ? *(const bf16x8*)(q + row * 32 + g * 8) : z8;
  }

  __syncthreads();

  char* vt = (char*)Vt[wave];
#pragma unroll
  for (int i = 0; i < 4; ++i) {
    int idx = i * 64 + lane;
    int t = idx >> 2, d0 = (idx & 3) << 3;
    if (t < 49) {
      bf16x8 vv = *(const bf16x8*)(v + t * 32 + d0);
#pragma unroll
      for (int j = 0; j < 8; ++j) {
        int d = d0 + j;
        *(__bf16*)(vt + d * 128 + ((t * 2) ^ ((d & 7) << 4))) = vv[j];
      }
    }
  }

  bf16x8 vf[2][2];
#pragma unroll
  for (int di = 0; di < 2; ++di) {
    int row = di * 16 + r;
#pragma unroll
    for (int t = 0; t < 2; ++t)
      vf[di][t] = *(const bf16x8*)(vt + row * 128 + (((t * 32 + g * 8) * 2) ^ ((row & 7) << 4)));
  }

  const __bf16* bp = bias_p + h * 4096;
  char* pw = (char*)Pl[wave];
  __bf16* aob = ao + (size_t)b * 25088 + h * 32;
  const int swz = (r & 7) << 4;
  const int mswz = (r & 7) << 2;

#pragma unroll
  for (int qi = 0; qi < 4; ++qi) {
    f32x4 s[4];
#pragma unroll
    for (int mi = 0; mi < 4; ++mi) s[mi] = MFMA16(kf[mi], qf[qi], z4);

    const int qrow = qi * 16 + r;
#pragma unroll
    for (int mi = 0; mi < 4; ++mi) {
      int c0 = mi * 16 + g * 4;
      bf16x4 b4 = *(const bf16x4*)(bp + qrow * 64 + c0);
      f32x4 m4 = *(const f32x4*)(maskl + qrow * 64 + (c0 ^ mswz));
#pragma unroll
      for (int jj = 0; jj < 4; ++jj)
        s[mi][jj] += (float)b4[jj] + m4[jj];
    }
    f32x4 aa = max4(max4(s[0], s[1]), max4(s[2], s[3]));
    float mx = fmaxf(fmaxf(aa[0], aa[1]), fmaxf(aa[2], aa[3]));
    mx = fmaxf(mx, __shfl_xor(mx, 16));
    mx = fmaxf(mx, __shfl_xor(mx, 32));
    float sum = 0.0f;
#pragma unroll
    for (int mi = 0; mi < 4; ++mi) {
#pragma unroll
      for (int jj = 0; jj < 4; ++jj) {
        float e = __expf(s[mi][jj] - mx);
        s[mi][jj] = e;
        sum += e;
      }
    }
    sum += __shfl_xor(sum, 16);
    sum += __shfl_xor(sum, 32);
    const float rinv = 1.0f / sum;

#pragma unroll
    for (int mi = 0; mi < 4; ++mi) {
      bf16x4 w;
#pragma unroll
      for (int jj = 0; jj < 4; ++jj) w[jj] = (__bf16)(s[mi][jj] * rinv);
      *(bf16x4*)(pw + r * 128 + (((mi * 16 + g * 4) * 2) ^ swz)) = w;
    }
    bf16x8 pa0 = *(const bf16x8*)(pw + r * 128 + ((g * 16) ^ swz));
    bf16x8 pa1 = *(const bf16x8*)(pw + r * 128 + ((64 + g * 16) ^ swz));

#pragma unroll
    for (int di = 0; di < 2; ++di) {
      f32x4 o = MFMA16(pa0, vf[di][0], z4);
      o = MFMA16(pa1, vf[di][1], o);
#pragma unroll
      for (int jj = 0; jj < 4; ++jj) {
        int qq = qi * 16 + g * 4 + jj;
        if (qq < 49)
          aob[(size_t)qq * 512 + di * 16 + r] = (__bf16)o[jj];
      }
    }
  }
}

// ---------------------------------------------------------------------------
extern "C" void kernel_launch(void* const* d_in, const int* in_sizes, int n_in,
                              void* d_out, int out_size, void* d_ws, size_t ws_size,
                              hipStream_t stream)
{
  const float* hs    = (const float*)d_in[0];
  const float* mask  = (const float*)d_in[1];
  const float* qkv_w = (const float*)d_in[2];
  const float* qkv_b = (const float*)d_in[3];
  const float* out_w = (const float*)d_in[4];
  const float* out_b = (const float*)d_in[5];
  const float* rpt   = (const float*)d_in[6];
  float* out = (float*)d_out;

  char* ws = (char*)d_ws;
  __bf16* hsb  = (__bf16*)(ws);                  // reused as attn-out after GEMM1
  __bf16* qb   = (__bf16*)(ws + 102760448);
  __bf16* kb   = (__bf16*)(ws + 205520896);
  __bf16* vb   = (__bf16*)(ws + 308281344);
  __bf16* qwb  = (__bf16*)(ws + 411041792);
  __bf16* owb  = (__bf16*)(ws + 412614656);
  __bf16* biasb= (__bf16*)(ws + 413138944);      // [16][64][64] bf16

  prep_k<<<4352, 256, 0, stream>>>(qkv_w, out_w, rpt, qwb, owb, biasb);
  cast_k<<<2048, 256, 0, stream>>>(hs, hsb, 6422528);
  gemm8p<0><<<2352, 512, 0, stream>>>(hsb, qwb, qkv_b, nullptr, qb, kb, vb,
                                      1536, 512);
  attn_k<<<8192, 256, 0, stream>>>(qb, kb, vb, biasb, mask, hsb);
  gemm8p<1><<<784, 512, 0, stream>>>(hsb, owb, out_b, out, nullptr, nullptr, nullptr,
                                     512, 512);
}